// Round 5
// baseline (484.178 us; speedup 1.0000x reference)
//
#include <hip/hip_runtime.h>

// CSA bf16-MFMA pipeline v5. B=4 H=W=128 C=128 heads=4 K2=9, hd=32.
// av: per 8x8 tile, per q: V_q^T via MFMA (waves split 2x2 over channels x locations),
// fold reads a 4x4 V-cache per 2x2 location quad (2.25x LDS reuse), then proj MFMA.
// ws: xb[65536][128] | attb[q][h][65536][10shorts] | wqkvb | wvb | wpb  (all bf16)

typedef short bf16x8 __attribute__((ext_vector_type(8)));
typedef float f32x4  __attribute__((ext_vector_type(4)));
typedef float v2f    __attribute__((ext_vector_type(2)));

#define SCALE 0.17677669529663687f   // hd^-0.5

__device__ __forceinline__ unsigned short f2bf(float f) {
  unsigned u = __float_as_uint(f);
  u = (u + 0x7fffu + ((u >> 16) & 1u)) >> 16;   // RNE
  return (unsigned short)u;
}
__device__ __forceinline__ float bf2f(unsigned short s) {
  return __uint_as_float(((unsigned)s) << 16);
}
__device__ __forceinline__ bf16x8 ldsFrag(const unsigned short* p) {
  union { bf16x8 v; unsigned u[4]; } r;
  const unsigned* s = (const unsigned*)p;
  r.u[0] = s[0]; r.u[1] = s[1]; r.u[2] = s[2]; r.u[3] = s[3];
  return r.v;
}
__device__ __forceinline__ bf16x8 ldg8(const unsigned short* p) {
  union { bf16x8 v; uint4 u; } r;
  r.u = *(const uint4*)p;
  return r.v;
}

// ---------------- K0: fp32 -> bf16 conversions ----------------
__global__ __launch_bounds__(256) void cvt_kernel(const float* __restrict__ x,
                                                  const float* __restrict__ wq,
                                                  const float* __restrict__ wv,
                                                  const float* __restrict__ wp,
                                                  unsigned short* __restrict__ xb,
                                                  unsigned short* __restrict__ wqb,
                                                  unsigned short* __restrict__ wvb,
                                                  unsigned short* __restrict__ wpb) {
  long i = ((long)blockIdx.x * 256 + threadIdx.x) * 4;
  if (i >= 8593920) return;
  const float* src; unsigned short* dst; long off;
  if (i < 8388608)      { src = x;  dst = xb;  off = i; }
  else if (i < 8430080) { src = wq; dst = wqb; off = i - 8388608; }
  else if (i < 8577536) { src = wv; dst = wvb; off = i - 8430080; }
  else                  { src = wp; dst = wpb; off = i - 8577536; }
  float4 v = *(const float4*)(src + off);
  ushort4 o;
  o.x = f2bf(v.x); o.y = f2bf(v.y); o.z = f2bf(v.z); o.w = f2bf(v.w);
  *(ushort4*)(dst + off) = o;
}

// ---------------- K1: att = softmax_q(x @ w_qkv^T * scale) ----------------
__global__ __launch_bounds__(256) void att_kernel(const unsigned short* __restrict__ xb,
                                                  const unsigned short* __restrict__ wqb,
                                                  unsigned* __restrict__ attb) {
  __shared__ unsigned short A[64 * 130];
  __shared__ unsigned short Bl[96 * 130];   // attile aliased on top
  __shared__ float lg[64][84];
  const int t = threadIdx.x;
  const long m0 = (long)blockIdx.x * 64;
  for (int i = t; i < 1024; i += 256) {
    int row = i >> 4, seg = i & 15;
    const uint4 v = *(const uint4*)(xb + (m0 + row) * 128 + seg * 8);
    unsigned* d = (unsigned*)(A + row * 130 + seg * 8);
    d[0] = v.x; d[1] = v.y; d[2] = v.z; d[3] = v.w;
  }
  const int wv = t >> 6, lane = t & 63, qd = lane >> 4, l15 = lane & 15;
  __syncthreads();
  bf16x8 af[4];
#pragma unroll
  for (int kk = 0; kk < 4; kk++)
    af[kk] = ldsFrag(A + (wv * 16 + l15) * 130 + kk * 32 + qd * 8);

  unsigned short* attile = Bl;              // [64][9][10] shorts, aliased
  for (int h = 0; h < 4; h++) {
    __syncthreads();
    for (int i = t; i < 1296; i += 256) {
      int row = i >> 4, seg = i & 15;
      const uint4 v = *(const uint4*)(wqb + (long)(h * 81 + row) * 128 + seg * 8);
      unsigned* d = (unsigned*)(Bl + row * 130 + seg * 8);
      d[0] = v.x; d[1] = v.y; d[2] = v.z; d[3] = v.w;
    }
    __syncthreads();
    f32x4 acc[6] = {};
#pragma unroll
    for (int kk = 0; kk < 4; kk++)
#pragma unroll
      for (int tn = 0; tn < 6; tn++) {
        bf16x8 bf = ldsFrag(Bl + (tn * 16 + l15) * 130 + kk * 32 + qd * 8);
        acc[tn] = __builtin_amdgcn_mfma_f32_16x16x32_bf16(af[kk], bf, acc[tn], 0, 0, 0);
      }
#pragma unroll
    for (int tn = 0; tn < 6; tn++)
#pragma unroll
      for (int r = 0; r < 4; r++) {
        int col = tn * 16 + l15;
        if (col < 81) lg[wv * 16 + qd * 4 + r][col] = acc[tn][r];
      }
    __syncthreads();
    for (int g = t; g < 576; g += 256) {
      int row = g / 9, p = g % 9;
      const float* L = &lg[row][p * 9];
      float mx = L[0];
#pragma unroll
      for (int q = 1; q < 9; q++) mx = fmaxf(mx, L[q]);
      float e[9], s = 0.f;
#pragma unroll
      for (int q = 0; q < 9; q++) { e[q] = __expf((L[q] - mx) * SCALE); s += e[q]; }
      float inv = 1.f / s;
#pragma unroll
      for (int q = 0; q < 9; q++) attile[row * 90 + q * 10 + p] = f2bf(e[q] * inv);
    }
    __syncthreads();
    // q-major coalesced store: attb[(q*4+h)][m0+n][5 dw]
#pragma unroll
    for (int k = 0; k < 12; k++) {
      int i = t + k * 256;
      if (i < 2880) {
        int q = i / 320, rem = i - q * 320, n = rem / 5, j = rem - n * 5;
        attb[((size_t)(q * 4 + h) * 65536 + m0 + n) * 5 + j] =
            ((const unsigned*)attile)[n * 45 + q * 5 + j];
      }
    }
  }
}

// ---------------- K2: fused V-MFMA + quad-fold + proj ----------------
__global__ __launch_bounds__(256, 2) void av_kernel(const unsigned short* __restrict__ xb,
                                                    const unsigned short* __restrict__ wvb,
                                                    const unsigned* __restrict__ attb,
                                                    const unsigned short* __restrict__ wpb,
                                                    float* __restrict__ out) {
  __shared__ unsigned short A[144 * 130];   // 37.4 KB : x halo 12x12 ; yb alias for proj
  __shared__ unsigned short S[100 * 130];   // 26.0 KB : V_q (channels-major per loc row)
  __shared__ unsigned aLs[2400];            // 9.6 KB  : att [h][100][6 dw]
  const int t = threadIdx.x;
  const int bb = blockIdx.z;
  const int r0 = blockIdx.y * 8, c0 = blockIdx.x * 8;
  const int l15 = t & 15, qd = (t >> 4) & 3, wvi = t >> 6;
  // V-phase wave roles: 2x2 split (channel-half mh, nt-half nh)
  const int mh = wvi & 1, nh = wvi >> 1;
  const int nt0 = nh * 4, ntn = nh ? 3 : 4;
  // fold-phase thread roles
  const int lq = l15, cg = wvi * 4 + qd, head = wvi;
  const int qr2 = (lq >> 2) * 2, qc2 = (lq & 3) * 2;
  const long nb = (long)bb * 16384;
  unsigned* Sdw = (unsigned*)S;

  // geometry of this wave's nt locations
  int mlr_[4], mlc_[4];
#pragma unroll
  for (int ntl = 0; ntl < 4; ntl++) {
    int ml = (nt0 + ntl) * 16 + l15;
    mlr_[ntl] = ml / 10; mlc_[ntl] = ml % 10;
  }

  // ---- stage x halo 12x12 -> A ----
#pragma unroll
  for (int k = 0; k < 9; k++) {
    int i = t + k * 256;                    // 2304 = 144 x 16
    int row = i >> 4, seg = i & 15;
    int gr = r0 - 2 + row / 12, gc = c0 - 2 + row % 12;
    uint4 v = make_uint4(0, 0, 0, 0);
    if (gr >= 0 && gr < 128 && gc >= 0 && gc < 128)
      v = *(const uint4*)(xb + (nb + gr * 128 + gc) * 128 + seg * 8);
    unsigned* d = (unsigned*)(A + row * 130 + seg * 8);
    d[0] = v.x; d[1] = v.y; d[2] = v.z; d[3] = v.w;
  }

  v2f y2[16];
#pragma unroll
  for (int i = 0; i < 16; i++) y2[i] = (v2f){0.f, 0.f};

  unsigned avv[8];
  bf16x8 wvf[4][4];

#define LOAD_A(qq)                                                                        \
  {                                                                                       \
    _Pragma("unroll") for (int k = 0; k < 8; k++) {                                       \
      int i = t + k * 256;                                                                \
      if (i < 2000) {                                                                     \
        int hh = i / 500, rem = i - hh * 500, row = rem / 5, j5 = rem - row * 5;          \
        int gr = r0 - 1 + row / 10, gc = c0 - 1 + row % 10;                               \
        avv[k] = (gr >= 0 && gr < 128 && gc >= 0 && gc < 128)                             \
                     ? attb[((size_t)((qq) * 4 + hh) * 65536 + nb + gr * 128 + gc) * 5 +  \
                            j5]                                                           \
                     : 0u;                                                                \
      }                                                                                   \
    }                                                                                     \
  }
#define LOAD_WV(qq)                                                                       \
  {                                                                                       \
    _Pragma("unroll") for (int m = 0; m < 4; m++)                                         \
    _Pragma("unroll") for (int kk = 0; kk < 4; kk++)                                      \
      wvf[m][kk] = ldg8(wvb + ((size_t)(qq) * 128 + mh * 64 + m * 16 + l15) * 128 +       \
                        kk * 32 + qd * 8);                                                \
  }

  LOAD_A(0)
  LOAD_WV(0)

  for (int q = 0; q < 9; q++) {
    const int oqr = q / 3 - 1, oqc = q % 3 - 1;
    __syncthreads();                        // fold(q-1) readers done

    // att regs -> aLs  [h][row][6dw rows, 5 used]
#pragma unroll
    for (int k = 0; k < 8; k++) {
      int i = t + k * 256;
      if (i < 2000) {
        int hh = i / 500, rem = i - hh * 500, row = rem / 5, j5 = rem - row * 5;
        aLs[hh * 600 + row * 6 + j5] = avv[k];
      }
    }

    // ---- V_q^T via MFMA: wave covers channels [mh*64, +64) x nts locations ----
    f32x4 acc[4][4];
#pragma unroll
    for (int m = 0; m < 4; m++)
#pragma unroll
      for (int ntl = 0; ntl < 4; ntl++) acc[m][ntl] = (f32x4){0.f, 0.f, 0.f, 0.f};
    for (int ntl = 0; ntl < ntn; ntl++) {
      int xr = (mlr_[ntl] + oqr + 1) * 12 + (mlc_[ntl] + oqc + 1);
      xr = xr > 143 ? 143 : xr;
      bf16x8 bx[4];
#pragma unroll
      for (int kk = 0; kk < 4; kk++)
        bx[kk] = ldsFrag(A + xr * 130 + kk * 32 + qd * 8);
#pragma unroll
      for (int m = 0; m < 4; m++)
#pragma unroll
        for (int kk = 0; kk < 4; kk++)
          acc[m][ntl] = __builtin_amdgcn_mfma_f32_16x16x32_bf16(wvf[m][kk], bx[kk],
                                                                acc[m][ntl], 0, 0, 0);
    }
    // store V^T: lane owns channels mh*64+m*16+qd*4..+3 of loc (nt0+ntl)*16+l15
    for (int ntl = 0; ntl < ntn; ntl++) {
      int loc = (nt0 + ntl) * 16 + l15;
      if (loc < 100) {
#pragma unroll
        for (int m = 0; m < 4; m++) {
          unsigned u0 = (unsigned)f2bf(acc[m][ntl][0]) | ((unsigned)f2bf(acc[m][ntl][1]) << 16);
          unsigned u1 = (unsigned)f2bf(acc[m][ntl][2]) | ((unsigned)f2bf(acc[m][ntl][3]) << 16);
          unsigned* d = Sdw + loc * 65 + mh * 32 + m * 8 + qd * 2;
          d[0] = u0; d[1] = u1;
        }
      }
    }
    __syncthreads();
    if (q < 8) { LOAD_A(q + 1) LOAD_WV(q + 1) }

    // ---- quad-fold: 4x4 V-cache, 2x2 locations, 8 channels ----
    uint4 Vc[4][4];
#pragma unroll
    for (int i = 0; i < 4; i++)
#pragma unroll
      for (int j = 0; j < 4; j++) {
        int mlp = (qr2 + i) * 10 + (qc2 + j);
        const unsigned* p = Sdw + mlp * 65 + cg * 4;
        Vc[i][j] = make_uint4(p[0], p[1], p[2], p[3]);
      }
    const unsigned short* aS = (const unsigned short*)aLs;
#pragma unroll
    for (int pi = 0; pi < 3; pi++)
#pragma unroll
      for (int pj = 0; pj < 3; pj++) {
        const int p = pi * 3 + pj;
#pragma unroll
        for (int d0 = 0; d0 < 2; d0++)
#pragma unroll
          for (int d1 = 0; d1 < 2; d1++) {
            const int ci = d0 + 2 - pi, cj = d1 + 2 - pj;
            const int mlp = (qr2 + ci) * 10 + (qc2 + cj);
            const float a = bf2f(aS[head * 1200 + mlp * 12 + p]);
            const v2f a2 = {a, a};
            const uint4 v = Vc[ci][cj];
            v2f xv;
            const int yi = (d0 * 2 + d1) * 4;
            xv.x = __uint_as_float(v.x << 16); xv.y = __uint_as_float(v.x & 0xffff0000u);
            y2[yi + 0] += a2 * xv;
            xv.x = __uint_as_float(v.y << 16); xv.y = __uint_as_float(v.y & 0xffff0000u);
            y2[yi + 1] += a2 * xv;
            xv.x = __uint_as_float(v.z << 16); xv.y = __uint_as_float(v.z & 0xffff0000u);
            y2[yi + 2] += a2 * xv;
            xv.x = __uint_as_float(v.w << 16); xv.y = __uint_as_float(v.w & 0xffff0000u);
            y2[yi + 3] += a2 * xv;
          }
      }
  }

  // ---- proj: out = y @ wp^T (yb aliases A) ----
  __syncthreads();
  unsigned short* yb = A;
  unsigned* ybdw = (unsigned*)yb;
#pragma unroll
  for (int d0 = 0; d0 < 2; d0++)
#pragma unroll
    for (int d1 = 0; d1 < 2; d1++) {
      int n = (qr2 + d0) * 8 + (qc2 + d1);
      const int yi = (d0 * 2 + d1) * 4;
#pragma unroll
      for (int dd = 0; dd < 4; dd++)
        ybdw[n * 65 + cg * 4 + dd] =
            (unsigned)f2bf(y2[yi + dd].x) | ((unsigned)f2bf(y2[yi + dd].y) << 16);
    }
  __syncthreads();
  f32x4 pacc[8] = {};
#pragma unroll
  for (int kk = 0; kk < 4; kk++) {
    bf16x8 afr = ldsFrag(yb + (wvi * 16 + l15) * 130 + kk * 32 + qd * 8);
#pragma unroll
    for (int tn = 0; tn < 8; tn++) {
      bf16x8 bfr = ldg8(wpb + (tn * 16 + l15) * 128 + kk * 32 + qd * 8);
      pacc[tn] = __builtin_amdgcn_mfma_f32_16x16x32_bf16(afr, bfr, pacc[tn], 0, 0, 0);
    }
  }
#pragma unroll
  for (int tn = 0; tn < 8; tn++)
#pragma unroll
    for (int r = 0; r < 4; r++) {
      int nl = wvi * 16 + qd * 4 + r;
      int col = tn * 16 + l15;
      out[(nb + (r0 + (nl >> 3)) * 128 + (c0 + (nl & 7))) * 128 + col] = pacc[tn][r];
    }
}

extern "C" void kernel_launch(void* const* d_in, const int* in_sizes, int n_in,
                              void* d_out, int out_size, void* d_ws, size_t ws_size,
                              hipStream_t stream) {
  const float* x  = (const float*)d_in[0];
  const float* wq = (const float*)d_in[1];
  const float* wv = (const float*)d_in[2];
  const float* wp = (const float*)d_in[3];
  char* w = (char*)d_ws;
  unsigned short* xb   = (unsigned short*)w;                  // 16,777,216 B
  unsigned*       attb = (unsigned*)(w + 16777216);           // 47,185,920 B
  unsigned short* wqb  = (unsigned short*)(w + 63963136);
  unsigned short* wvb  = wqb + 41472;
  unsigned short* wpb  = wvb + 147456;

  cvt_kernel<<<8393, 256, 0, stream>>>(x, wq, wv, wp, xb, wqb, wvb, wpb);
  att_kernel<<<1024, 256, 0, stream>>>(xb, wqb, attb);
  dim3 g3(16, 16, 4);
  av_kernel<<<g3, 256, 0, stream>>>(xb, wvb, attb, wpb, (float*)d_out);
}

// Round 6
// 216.287 us; speedup vs baseline: 2.2386x; 2.2386x over previous
//
#include <hip/hip_runtime.h>

// CSA bf16-MFMA pipeline v6. B=4 H=W=128 C=128 heads=4 K2=9, hd=32.
// av = R4 structure (fused V-MFMA + fold + proj, VGPR-safe) with 16B-aligned LDS rows
// (stride 136 shorts) so all hot LDS ops are b128/b64. attb is q,h-major (R5 layout).
// ws: xb[65536][128] | attb[q*4+h][65536][5dw] | wqkvb | wvb | wpb  (all bf16)

typedef short bf16x8 __attribute__((ext_vector_type(8)));
typedef float f32x4  __attribute__((ext_vector_type(4)));
typedef float v2f    __attribute__((ext_vector_type(2)));

#define SCALE 0.17677669529663687f   // hd^-0.5

__device__ __forceinline__ unsigned short f2bf(float f) {
  unsigned u = __float_as_uint(f);
  u = (u + 0x7fffu + ((u >> 16) & 1u)) >> 16;   // RNE
  return (unsigned short)u;
}
__device__ __forceinline__ float bf2f(unsigned short s) {
  return __uint_as_float(((unsigned)s) << 16);
}
__device__ __forceinline__ bf16x8 ld16(const unsigned short* p) {   // 16B-aligned
  union { bf16x8 v; uint4 u; } r;
  r.u = *(const uint4*)p;
  return r.v;
}

// ---------------- K0: fp32 -> bf16 conversions ----------------
__global__ __launch_bounds__(256) void cvt_kernel(const float* __restrict__ x,
                                                  const float* __restrict__ wq,
                                                  const float* __restrict__ wv,
                                                  const float* __restrict__ wp,
                                                  unsigned short* __restrict__ xb,
                                                  unsigned short* __restrict__ wqb,
                                                  unsigned short* __restrict__ wvb,
                                                  unsigned short* __restrict__ wpb) {
  long i = ((long)blockIdx.x * 256 + threadIdx.x) * 4;
  if (i >= 8593920) return;
  const float* src; unsigned short* dst; long off;
  if (i < 8388608)      { src = x;  dst = xb;  off = i; }
  else if (i < 8430080) { src = wq; dst = wqb; off = i - 8388608; }
  else if (i < 8577536) { src = wv; dst = wvb; off = i - 8430080; }
  else                  { src = wp; dst = wpb; off = i - 8577536; }
  float4 v = *(const float4*)(src + off);
  ushort4 o;
  o.x = f2bf(v.x); o.y = f2bf(v.y); o.z = f2bf(v.z); o.w = f2bf(v.w);
  *(ushort4*)(dst + off) = o;
}

// ---------------- K1: att = softmax_q(x @ w_qkv^T * scale) ----------------
__global__ __launch_bounds__(256) void att_kernel(const unsigned short* __restrict__ xb,
                                                  const unsigned short* __restrict__ wqb,
                                                  unsigned* __restrict__ attb) {
  __shared__ unsigned short A[64 * 136];
  __shared__ unsigned short Bl[96 * 136];   // attile aliased on top
  __shared__ float lg[64][84];
  const int t = threadIdx.x;
  const long m0 = (long)blockIdx.x * 64;
  for (int i = t; i < 1024; i += 256) {
    int row = i >> 4, seg = i & 15;
    const uint4 v = *(const uint4*)(xb + (m0 + row) * 128 + seg * 8);
    *(uint4*)((unsigned*)A + row * 68 + seg * 4) = v;
  }
  const int wv = t >> 6, lane = t & 63, qd = lane >> 4, l15 = lane & 15;
  __syncthreads();
  bf16x8 af[4];
#pragma unroll
  for (int kk = 0; kk < 4; kk++)
    af[kk] = ld16(A + (wv * 16 + l15) * 136 + kk * 32 + qd * 8);

  unsigned short* attile = Bl;              // [64][9][10] shorts, aliased
  for (int h = 0; h < 4; h++) {
    __syncthreads();
    for (int i = t; i < 1296; i += 256) {
      int row = i >> 4, seg = i & 15;
      const uint4 v = *(const uint4*)(wqb + (long)(h * 81 + row) * 128 + seg * 8);
      *(uint4*)((unsigned*)Bl + row * 68 + seg * 4) = v;
    }
    __syncthreads();
    f32x4 acc[6] = {};
#pragma unroll
    for (int kk = 0; kk < 4; kk++)
#pragma unroll
      for (int tn = 0; tn < 6; tn++) {
        bf16x8 bf = ld16(Bl + (tn * 16 + l15) * 136 + kk * 32 + qd * 8);
        acc[tn] = __builtin_amdgcn_mfma_f32_16x16x32_bf16(af[kk], bf, acc[tn], 0, 0, 0);
      }
#pragma unroll
    for (int tn = 0; tn < 6; tn++)
#pragma unroll
      for (int r = 0; r < 4; r++) {
        int col = tn * 16 + l15;
        if (col < 81) lg[wv * 16 + qd * 4 + r][col] = acc[tn][r];
      }
    __syncthreads();
    for (int g = t; g < 576; g += 256) {
      int row = g / 9, p = g % 9;
      const float* L = &lg[row][p * 9];
      float mx = L[0];
#pragma unroll
      for (int q = 1; q < 9; q++) mx = fmaxf(mx, L[q]);
      float e[9], s = 0.f;
#pragma unroll
      for (int q = 0; q < 9; q++) { e[q] = __expf((L[q] - mx) * SCALE); s += e[q]; }
      float inv = 1.f / s;
#pragma unroll
      for (int q = 0; q < 9; q++) attile[row * 90 + q * 10 + p] = f2bf(e[q] * inv);
    }
    __syncthreads();
    // q-major coalesced store: attb[(q*4+h)][m0+n][5 dw]
#pragma unroll
    for (int k = 0; k < 12; k++) {
      int i = t + k * 256;
      if (i < 2880) {
        int q = i / 320, rem = i - q * 320, n = rem / 5, j = rem - n * 5;
        attb[((size_t)(q * 4 + h) * 65536 + m0 + n) * 5 + j] =
            ((const unsigned*)attile)[n * 45 + q * 5 + j];
      }
    }
  }
}

// ---------------- K2: fused V-MFMA + fold + proj (R4 structure, aligned LDS) ----------
__global__ __launch_bounds__(256, 2) void av_kernel(const unsigned short* __restrict__ xb,
                                                    const unsigned short* __restrict__ wvb,
                                                    const unsigned* __restrict__ attb,
                                                    const unsigned short* __restrict__ wpb,
                                                    float* __restrict__ out) {
  __shared__ unsigned short A[144 * 136];   // 39.2 KB : x halo 12x12 ; yb alias for proj
  __shared__ unsigned short S[100 * 136];   // 27.2 KB : V_q (channel shorts per loc row)
  __shared__ unsigned aLs[2400];            // 9.6 KB  : att [h][100][6 dw]
  const int t = threadIdx.x;
  const int bb = blockIdx.z;
  const int r0 = blockIdx.y * 8, c0 = blockIdx.x * 8;
  const int l15 = t & 15, qd = (t >> 4) & 3, wvi = t >> 6;
  const int n = wvi * 16 + l15, lr = n >> 3, lc = n & 7;
  const long nb = (long)bb * 16384;
  unsigned* Sdw = (unsigned*)S;
  unsigned* Adw = (unsigned*)A;

  int mlr_[7], mlc_[7];
#pragma unroll
  for (int nt = 0; nt < 7; nt++) {
    int ml = nt * 16 + l15;
    mlr_[nt] = ml / 10; mlc_[nt] = ml % 10;
  }

  // ---- stage x halo 12x12 -> A ----
#pragma unroll
  for (int k = 0; k < 9; k++) {
    int i = t + k * 256;                    // 2304 = 144 x 16
    int row = i >> 4, seg = i & 15;
    int gr = r0 - 2 + row / 12, gc = c0 - 2 + row % 12;
    uint4 v = make_uint4(0, 0, 0, 0);
    if (gr >= 0 && gr < 128 && gc >= 0 && gc < 128)
      v = *(const uint4*)(xb + (nb + gr * 128 + gc) * 128 + seg * 8);
    *(uint4*)(Adw + row * 68 + seg * 4) = v;
  }

  v2f y2[16];
#pragma unroll
  for (int i = 0; i < 16; i++) y2[i] = (v2f){0.f, 0.f};

  unsigned avv[8];
  bf16x8 wvf[2][4];

#define LOAD_A(qq)                                                                        \
  {                                                                                       \
    _Pragma("unroll") for (int k = 0; k < 8; k++) {                                       \
      int i = t + k * 256;                                                                \
      if (i < 2000) {                                                                     \
        int hh = i / 500, rem = i - hh * 500, row = rem / 5, j5 = rem - row * 5;          \
        int gr = r0 - 1 + row / 10, gc = c0 - 1 + row % 10;                               \
        avv[k] = (gr >= 0 && gr < 128 && gc >= 0 && gc < 128)                             \
                     ? attb[((size_t)((qq) * 4 + hh) * 65536 + nb + gr * 128 + gc) * 5 +  \
                            j5]                                                           \
                     : 0u;                                                                \
      }                                                                                   \
    }                                                                                     \
  }
#define LOAD_WV(qq)                                                                       \
  {                                                                                       \
    _Pragma("unroll") for (int m = 0; m < 2; m++)                                         \
    _Pragma("unroll") for (int kk = 0; kk < 4; kk++)                                      \
      wvf[m][kk] = *(const bf16x8*)(wvb + ((size_t)(qq) * 128 + (wvi * 2 + m) * 16 +      \
                                           l15) * 128 + kk * 32 + qd * 8);                \
  }

  LOAD_A(0)
  LOAD_WV(0)

  for (int q = 0; q < 9; q++) {
    const int oqr = q / 3 - 1, oqc = q % 3 - 1;
    __syncthreads();                        // fold(q-1) readers done

    // att regs -> aLs [h][row][6dw]
#pragma unroll
    for (int k = 0; k < 8; k++) {
      int i = t + k * 256;
      if (i < 2000) {
        int hh = i / 500, rem = i - hh * 500, row = rem / 5, j5 = rem - row * 5;
        aLs[hh * 600 + row * 6 + j5] = avv[k];
      }
    }

    // ---- V_q^T via MFMA: D[row=channel][col=location] ----
    f32x4 acc[2][7];
#pragma unroll
    for (int m = 0; m < 2; m++)
#pragma unroll
      for (int nt = 0; nt < 7; nt++) acc[m][nt] = (f32x4){0.f, 0.f, 0.f, 0.f};
#pragma unroll
    for (int nt = 0; nt < 7; nt++) {
      int xr = (mlr_[nt] + oqr + 1) * 12 + (mlc_[nt] + oqc + 1);
      xr = xr > 143 ? 143 : xr;             // pad rows (ml>=100) clamp
      bf16x8 bx[4];
#pragma unroll
      for (int kk = 0; kk < 4; kk++)
        bx[kk] = ld16(A + xr * 136 + kk * 32 + qd * 8);
#pragma unroll
      for (int m = 0; m < 2; m++)
#pragma unroll
        for (int kk = 0; kk < 4; kk++)
          acc[m][nt] = __builtin_amdgcn_mfma_f32_16x16x32_bf16(wvf[m][kk], bx[kk],
                                                               acc[m][nt], 0, 0, 0);
    }
    // store V^T: lane owns channels (wvi*2+m)*16+qd*4..+3 of loc nt*16+l15
#pragma unroll
    for (int m = 0; m < 2; m++)
#pragma unroll
      for (int nt = 0; nt < 7; nt++) {
        int loc = nt * 16 + l15;
        if (loc < 100) {
          int mt = wvi * 2 + m;
          unsigned u0 = (unsigned)f2bf(acc[m][nt][0]) | ((unsigned)f2bf(acc[m][nt][1]) << 16);
          unsigned u1 = (unsigned)f2bf(acc[m][nt][2]) | ((unsigned)f2bf(acc[m][nt][3]) << 16);
          *(uint2*)(Sdw + loc * 68 + mt * 8 + qd * 2) = make_uint2(u0, u1);
        }
      }
    __syncthreads();
    if (q < 8) { LOAD_A(q + 1) LOAD_WV(q + 1) }   // overlap with fold

    // ---- fold: y[n, c(qd)] += att[n',qd,p,q] * V_q[n'] ; 4 x b128 per p ----
    const unsigned short* aS = (const unsigned short*)aLs;
#pragma unroll
    for (int p = 0; p < 9; p++) {
      const int em = 1 - p / 3, ec = 1 - p % 3;
      const int ml = (lr + em + 1) * 10 + (lc + ec + 1);
      const float a = bf2f(aS[qd * 1200 + ml * 12 + p]);
      const v2f a2 = {a, a};
      const uint4* Sr = (const uint4*)(Sdw + ml * 68 + (qd << 4));
#pragma unroll
      for (int v4 = 0; v4 < 4; v4++) {
        const uint4 u = Sr[v4];
        v2f xv;
        const int yi = v4 * 4;
        xv.x = __uint_as_float(u.x << 16); xv.y = __uint_as_float(u.x & 0xffff0000u);
        y2[yi + 0] += a2 * xv;
        xv.x = __uint_as_float(u.y << 16); xv.y = __uint_as_float(u.y & 0xffff0000u);
        y2[yi + 1] += a2 * xv;
        xv.x = __uint_as_float(u.z << 16); xv.y = __uint_as_float(u.z & 0xffff0000u);
        y2[yi + 2] += a2 * xv;
        xv.x = __uint_as_float(u.w << 16); xv.y = __uint_as_float(u.w & 0xffff0000u);
        y2[yi + 3] += a2 * xv;
      }
    }
  }

  // ---- proj: out = y @ wp^T (yb aliases A) ----
  __syncthreads();
  unsigned short* yb = A;
  {
    uint4 pk[4];
#pragma unroll
    for (int v4 = 0; v4 < 4; v4++) {
      pk[v4].x = (unsigned)f2bf(y2[v4 * 4 + 0].x) | ((unsigned)f2bf(y2[v4 * 4 + 0].y) << 16);
      pk[v4].y = (unsigned)f2bf(y2[v4 * 4 + 1].x) | ((unsigned)f2bf(y2[v4 * 4 + 1].y) << 16);
      pk[v4].z = (unsigned)f2bf(y2[v4 * 4 + 2].x) | ((unsigned)f2bf(y2[v4 * 4 + 2].y) << 16);
      pk[v4].w = (unsigned)f2bf(y2[v4 * 4 + 3].x) | ((unsigned)f2bf(y2[v4 * 4 + 3].y) << 16);
    }
    uint4* dst = (uint4*)(Adw + n * 68 + (qd << 4));
#pragma unroll
    for (int v4 = 0; v4 < 4; v4++) dst[v4] = pk[v4];
  }
  __syncthreads();
  f32x4 pacc[8] = {};
#pragma unroll
  for (int kk = 0; kk < 4; kk++) {
    bf16x8 afr = ld16(yb + (wvi * 16 + l15) * 136 + kk * 32 + qd * 8);
#pragma unroll
    for (int tn = 0; tn < 8; tn++) {
      bf16x8 bfr = *(const bf16x8*)(wpb + (tn * 16 + l15) * 128 + kk * 32 + qd * 8);
      pacc[tn] = __builtin_amdgcn_mfma_f32_16x16x32_bf16(afr, bfr, pacc[tn], 0, 0, 0);
    }
  }
#pragma unroll
  for (int tn = 0; tn < 8; tn++)
#pragma unroll
    for (int r = 0; r < 4; r++) {
      int nl = wvi * 16 + qd * 4 + r;
      int col = tn * 16 + l15;
      out[(nb + (r0 + (nl >> 3)) * 128 + (c0 + (nl & 7))) * 128 + col] = pacc[tn][r];
    }
}

extern "C" void kernel_launch(void* const* d_in, const int* in_sizes, int n_in,
                              void* d_out, int out_size, void* d_ws, size_t ws_size,
                              hipStream_t stream) {
  const float* x  = (const float*)d_in[0];
  const float* wq = (const float*)d_in[1];
  const float* wv = (const float*)d_in[2];
  const float* wp = (const float*)d_in[3];
  char* w = (char*)d_ws;
  unsigned short* xb   = (unsigned short*)w;                  // 16,777,216 B
  unsigned*       attb = (unsigned*)(w + 16777216);           // 47,185,920 B
  unsigned short* wqb  = (unsigned short*)(w + 63963136);
  unsigned short* wvb  = wqb + 41472;
  unsigned short* wpb  = wvb + 147456;

  cvt_kernel<<<8393, 256, 0, stream>>>(x, wq, wv, wp, xb, wqb, wvb, wpb);
  att_kernel<<<1024, 256, 0, stream>>>(xb, wqb, attb);
  dim3 g3(16, 16, 4);
  av_kernel<<<g3, 256, 0, stream>>>(xb, wvb, attb, wpb, (float*)d_out);
}

// Round 7
// 214.828 us; speedup vs baseline: 2.2538x; 1.0068x over previous
//
#include <hip/hip_runtime.h>

// CSA bf16-MFMA pipeline v7. B=4 H=W=128 C=128 heads=4 K2=9, hd=32.
// v6 + (a) v_perm-based bf16 packing (3 VALU/dw vs ~18), (b) xb eliminated:
// att/av stage x fp32->bf16 in-flight; cvt converts weights only.
// ws: attb[q*4+h][65536][5dw] | wqkvb | wvb | wpb  (weights bf16)

typedef short bf16x8 __attribute__((ext_vector_type(8)));
typedef float f32x4  __attribute__((ext_vector_type(4)));
typedef float v2f    __attribute__((ext_vector_type(2)));

#define SCALE 0.17677669529663687f   // hd^-0.5

__device__ __forceinline__ unsigned short f2bf(float f) {   // RNE (weights only)
  unsigned u = __float_as_uint(f);
  u = (u + 0x7fffu + ((u >> 16) & 1u)) >> 16;
  return (unsigned short)u;
}
__device__ __forceinline__ float bf2f(unsigned short s) {
  return __uint_as_float(((unsigned)s) << 16);
}
// pack two f32 -> bf16 pair (round half-up): 2 add + 1 v_perm
__device__ __forceinline__ unsigned pk2bf(float lo, float hi) {
  unsigned a = __float_as_uint(lo) + 0x8000u;
  unsigned b = __float_as_uint(hi) + 0x8000u;
  return __builtin_amdgcn_perm(b, a, 0x07060302u);  // [b.hi16 : a.hi16]
}
__device__ __forceinline__ bf16x8 ld16(const unsigned short* p) {   // 16B-aligned
  union { bf16x8 v; uint4 u; } r;
  r.u = *(const uint4*)p;
  return r.v;
}

// ---------------- K0: fp32 -> bf16 weight conversion ----------------
__global__ __launch_bounds__(256) void cvt_kernel(const float* __restrict__ wq,
                                                  const float* __restrict__ wv,
                                                  const float* __restrict__ wp,
                                                  unsigned short* __restrict__ wqb,
                                                  unsigned short* __restrict__ wvb,
                                                  unsigned short* __restrict__ wpb) {
  long i = ((long)blockIdx.x * 256 + threadIdx.x) * 4;
  if (i >= 205312) return;
  const float* src; unsigned short* dst; long off;
  if (i < 41472)       { src = wq; dst = wqb; off = i; }
  else if (i < 188928) { src = wv; dst = wvb; off = i - 41472; }
  else                 { src = wp; dst = wpb; off = i - 188928; }
  float4 v = *(const float4*)(src + off);
  ushort4 o;
  o.x = f2bf(v.x); o.y = f2bf(v.y); o.z = f2bf(v.z); o.w = f2bf(v.w);
  *(ushort4*)(dst + off) = o;
}

// ---------------- K1: att = softmax_q(x @ w_qkv^T * scale) ----------------
__global__ __launch_bounds__(256) void att_kernel(const float* __restrict__ x,
                                                  const unsigned short* __restrict__ wqb,
                                                  unsigned* __restrict__ attb) {
  __shared__ unsigned short A[64 * 136];
  __shared__ unsigned short Bl[96 * 136];   // attile aliased on top
  __shared__ float lg[64][84];
  const int t = threadIdx.x;
  const long m0 = (long)blockIdx.x * 64;
  // stage x fp32 -> bf16: 64 rows x 32 segs of 4 floats
#pragma unroll
  for (int k = 0; k < 8; k++) {
    int i = t + k * 256;
    int row = i >> 5, seg = i & 31;
    float4 v = *(const float4*)(x + (m0 + row) * 128 + seg * 4);
    *(uint2*)((unsigned*)A + row * 68 + seg * 2) =
        make_uint2(pk2bf(v.x, v.y), pk2bf(v.z, v.w));
  }
  const int wv = t >> 6, lane = t & 63, qd = lane >> 4, l15 = lane & 15;
  __syncthreads();
  bf16x8 af[4];
#pragma unroll
  for (int kk = 0; kk < 4; kk++)
    af[kk] = ld16(A + (wv * 16 + l15) * 136 + kk * 32 + qd * 8);

  unsigned short* attile = Bl;              // [64][9][10] shorts, aliased
  for (int h = 0; h < 4; h++) {
    __syncthreads();
    for (int i = t; i < 1296; i += 256) {
      int row = i >> 4, seg = i & 15;
      const uint4 v = *(const uint4*)(wqb + (long)(h * 81 + row) * 128 + seg * 8);
      *(uint4*)((unsigned*)Bl + row * 68 + seg * 4) = v;
    }
    __syncthreads();
    f32x4 acc[6] = {};
#pragma unroll
    for (int kk = 0; kk < 4; kk++)
#pragma unroll
      for (int tn = 0; tn < 6; tn++) {
        bf16x8 bf = ld16(Bl + (tn * 16 + l15) * 136 + kk * 32 + qd * 8);
        acc[tn] = __builtin_amdgcn_mfma_f32_16x16x32_bf16(af[kk], bf, acc[tn], 0, 0, 0);
      }
#pragma unroll
    for (int tn = 0; tn < 6; tn++)
#pragma unroll
      for (int r = 0; r < 4; r++) {
        int col = tn * 16 + l15;
        if (col < 81) lg[wv * 16 + qd * 4 + r][col] = acc[tn][r];
      }
    __syncthreads();
    for (int g = t; g < 576; g += 256) {
      int row = g / 9, p = g % 9;
      const float* L = &lg[row][p * 9];
      float mx = L[0];
#pragma unroll
      for (int q = 1; q < 9; q++) mx = fmaxf(mx, L[q]);
      float e[9], s = 0.f;
#pragma unroll
      for (int q = 0; q < 9; q++) { e[q] = __expf((L[q] - mx) * SCALE); s += e[q]; }
      float inv = 1.f / s;
#pragma unroll
      for (int q = 0; q < 9; q++) attile[row * 90 + q * 10 + p] = f2bf(e[q] * inv);
    }
    __syncthreads();
    // q-major coalesced store: attb[(q*4+h)][m0+n][5 dw]
#pragma unroll
    for (int k = 0; k < 12; k++) {
      int i = t + k * 256;
      if (i < 2880) {
        int q = i / 320, rem = i - q * 320, n = rem / 5, j = rem - n * 5;
        attb[((size_t)(q * 4 + h) * 65536 + m0 + n) * 5 + j] =
            ((const unsigned*)attile)[n * 45 + q * 5 + j];
      }
    }
  }
}

// ---------------- K2: fused V-MFMA + fold + proj ----------------
__global__ __launch_bounds__(256, 2) void av_kernel(const float* __restrict__ x,
                                                    const unsigned short* __restrict__ wvb,
                                                    const unsigned* __restrict__ attb,
                                                    const unsigned short* __restrict__ wpb,
                                                    float* __restrict__ out) {
  __shared__ unsigned short A[144 * 136];   // 39.2 KB : x halo 12x12 ; yb alias for proj
  __shared__ unsigned short S[100 * 136];   // 27.2 KB : V_q (channel shorts per loc row)
  __shared__ unsigned aLs[2400];            // 9.6 KB  : att [h][100][6 dw]
  const int t = threadIdx.x;
  const int bb = blockIdx.z;
  const int r0 = blockIdx.y * 8, c0 = blockIdx.x * 8;
  const int l15 = t & 15, qd = (t >> 4) & 3, wvi = t >> 6;
  const int n = wvi * 16 + l15, lr = n >> 3, lc = n & 7;
  const long nb = (long)bb * 16384;
  unsigned* Sdw = (unsigned*)S;
  unsigned* Adw = (unsigned*)A;

  int mlr_[7], mlc_[7];
#pragma unroll
  for (int nt = 0; nt < 7; nt++) {
    int ml = nt * 16 + l15;
    mlr_[nt] = ml / 10; mlc_[nt] = ml % 10;
  }

  // ---- stage x halo 12x12 fp32 -> bf16 : 144 rows x 32 segs ----
#pragma unroll
  for (int k = 0; k < 18; k++) {
    int i = t + k * 256;                    // 4608 = 144 x 32
    int row = i >> 5, seg = i & 31;
    int gr = r0 - 2 + row / 12, gc = c0 - 2 + row % 12;
    float4 v = make_float4(0.f, 0.f, 0.f, 0.f);
    if (gr >= 0 && gr < 128 && gc >= 0 && gc < 128)
      v = *(const float4*)(x + (nb + gr * 128 + gc) * 128 + seg * 4);
    *(uint2*)(Adw + row * 68 + seg * 2) = make_uint2(pk2bf(v.x, v.y), pk2bf(v.z, v.w));
  }

  v2f y2[16];
#pragma unroll
  for (int i = 0; i < 16; i++) y2[i] = (v2f){0.f, 0.f};

  unsigned avv[8];
  bf16x8 wvf[2][4];

#define LOAD_A(qq)                                                                        \
  {                                                                                       \
    _Pragma("unroll") for (int k = 0; k < 8; k++) {                                       \
      int i = t + k * 256;                                                                \
      if (i < 2000) {                                                                     \
        int hh = i / 500, rem = i - hh * 500, row = rem / 5, j5 = rem - row * 5;          \
        int gr = r0 - 1 + row / 10, gc = c0 - 1 + row % 10;                               \
        avv[k] = (gr >= 0 && gr < 128 && gc >= 0 && gc < 128)                             \
                     ? attb[((size_t)((qq) * 4 + hh) * 65536 + nb + gr * 128 + gc) * 5 +  \
                            j5]                                                           \
                     : 0u;                                                                \
      }                                                                                   \
    }                                                                                     \
  }
#define LOAD_WV(qq)                                                                       \
  {                                                                                       \
    _Pragma("unroll") for (int m = 0; m < 2; m++)                                         \
    _Pragma("unroll") for (int kk = 0; kk < 4; kk++)                                      \
      wvf[m][kk] = *(const bf16x8*)(wvb + ((size_t)(qq) * 128 + (wvi * 2 + m) * 16 +      \
                                           l15) * 128 + kk * 32 + qd * 8);                \
  }

  LOAD_A(0)
  LOAD_WV(0)

  for (int q = 0; q < 9; q++) {
    const int oqr = q / 3 - 1, oqc = q % 3 - 1;
    __syncthreads();                        // fold(q-1) readers done

    // att regs -> aLs [h][row][6dw]
#pragma unroll
    for (int k = 0; k < 8; k++) {
      int i = t + k * 256;
      if (i < 2000) {
        int hh = i / 500, rem = i - hh * 500, row = rem / 5, j5 = rem - row * 5;
        aLs[hh * 600 + row * 6 + j5] = avv[k];
      }
    }

    // ---- V_q^T via MFMA: D[row=channel][col=location] ----
    f32x4 acc[2][7];
#pragma unroll
    for (int m = 0; m < 2; m++)
#pragma unroll
      for (int nt = 0; nt < 7; nt++) acc[m][nt] = (f32x4){0.f, 0.f, 0.f, 0.f};
#pragma unroll
    for (int nt = 0; nt < 7; nt++) {
      int xr = (mlr_[nt] + oqr + 1) * 12 + (mlc_[nt] + oqc + 1);
      xr = xr > 143 ? 143 : xr;             // pad rows (ml>=100) clamp
      bf16x8 bx[4];
#pragma unroll
      for (int kk = 0; kk < 4; kk++)
        bx[kk] = ld16(A + xr * 136 + kk * 32 + qd * 8);
#pragma unroll
      for (int m = 0; m < 2; m++)
#pragma unroll
        for (int kk = 0; kk < 4; kk++)
          acc[m][nt] = __builtin_amdgcn_mfma_f32_16x16x32_bf16(wvf[m][kk], bx[kk],
                                                               acc[m][nt], 0, 0, 0);
    }
    // store V^T: lane owns channels (wvi*2+m)*16+qd*4..+3 of loc nt*16+l15
#pragma unroll
    for (int m = 0; m < 2; m++)
#pragma unroll
      for (int nt = 0; nt < 7; nt++) {
        int loc = nt * 16 + l15;
        if (loc < 100) {
          int mt = wvi * 2 + m;
          *(uint2*)(Sdw + loc * 68 + mt * 8 + qd * 2) =
              make_uint2(pk2bf(acc[m][nt][0], acc[m][nt][1]),
                         pk2bf(acc[m][nt][2], acc[m][nt][3]));
        }
      }
    __syncthreads();
    if (q < 8) { LOAD_A(q + 1) LOAD_WV(q + 1) }   // overlap with fold

    // ---- fold: y[n, c(qd)] += att[n',qd,p,q] * V_q[n'] ; 4 x b128 per p ----
    const unsigned short* aS = (const unsigned short*)aLs;
#pragma unroll
    for (int p = 0; p < 9; p++) {
      const int em = 1 - p / 3, ec = 1 - p % 3;
      const int ml = (lr + em + 1) * 10 + (lc + ec + 1);
      const float a = bf2f(aS[qd * 1200 + ml * 12 + p]);
      const v2f a2 = {a, a};
      const uint4* Sr = (const uint4*)(Sdw + ml * 68 + (qd << 4));
#pragma unroll
      for (int v4 = 0; v4 < 4; v4++) {
        const uint4 u = Sr[v4];
        v2f xv;
        const int yi = v4 * 4;
        xv.x = __uint_as_float(u.x << 16); xv.y = __uint_as_float(u.x & 0xffff0000u);
        y2[yi + 0] += a2 * xv;
        xv.x = __uint_as_float(u.y << 16); xv.y = __uint_as_float(u.y & 0xffff0000u);
        y2[yi + 1] += a2 * xv;
        xv.x = __uint_as_float(u.z << 16); xv.y = __uint_as_float(u.z & 0xffff0000u);
        y2[yi + 2] += a2 * xv;
        xv.x = __uint_as_float(u.w << 16); xv.y = __uint_as_float(u.w & 0xffff0000u);
        y2[yi + 3] += a2 * xv;
      }
    }
  }

  // ---- proj: out = y @ wp^T (yb aliases A) ----
  __syncthreads();
  unsigned short* yb = A;
  {
    uint4 pk[4];
#pragma unroll
    for (int v4 = 0; v4 < 4; v4++) {
      pk[v4].x = pk2bf(y2[v4 * 4 + 0].x, y2[v4 * 4 + 0].y);
      pk[v4].y = pk2bf(y2[v4 * 4 + 1].x, y2[v4 * 4 + 1].y);
      pk[v4].z = pk2bf(y2[v4 * 4 + 2].x, y2[v4 * 4 + 2].y);
      pk[v4].w = pk2bf(y2[v4 * 4 + 3].x, y2[v4 * 4 + 3].y);
    }
    uint4* dst = (uint4*)(Adw + n * 68 + (qd << 4));
#pragma unroll
    for (int v4 = 0; v4 < 4; v4++) dst[v4] = pk[v4];
  }
  __syncthreads();
  f32x4 pacc[8] = {};
#pragma unroll
  for (int kk = 0; kk < 4; kk++) {
    bf16x8 afr = ld16(yb + (wvi * 16 + l15) * 136 + kk * 32 + qd * 8);
#pragma unroll
    for (int tn = 0; tn < 8; tn++) {
      bf16x8 bfr = *(const bf16x8*)(wpb + (tn * 16 + l15) * 128 + kk * 32 + qd * 8);
      pacc[tn] = __builtin_amdgcn_mfma_f32_16x16x32_bf16(afr, bfr, pacc[tn], 0, 0, 0);
    }
  }
#pragma unroll
  for (int tn = 0; tn < 8; tn++)
#pragma unroll
    for (int r = 0; r < 4; r++) {
      int nl = wvi * 16 + qd * 4 + r;
      int col = tn * 16 + l15;
      out[(nb + (r0 + (nl >> 3)) * 128 + (c0 + (nl & 7))) * 128 + col] = pacc[tn][r];
    }
}

extern "C" void kernel_launch(void* const* d_in, const int* in_sizes, int n_in,
                              void* d_out, int out_size, void* d_ws, size_t ws_size,
                              hipStream_t stream) {
  const float* x  = (const float*)d_in[0];
  const float* wq = (const float*)d_in[1];
  const float* wv = (const float*)d_in[2];
  const float* wp = (const float*)d_in[3];
  char* w = (char*)d_ws;
  unsigned*       attb = (unsigned*)w;                        // 47,185,920 B
  unsigned short* wqb  = (unsigned short*)(w + 47185920);     // 82,944 B
  unsigned short* wvb  = wqb + 41472;                         // 294,912 B
  unsigned short* wpb  = wvb + 147456;                        // 32,768 B

  cvt_kernel<<<201, 256, 0, stream>>>(wq, wv, wp, wqb, wvb, wpb);
  att_kernel<<<1024, 256, 0, stream>>>(x, wqb, attb);
  dim3 g3(16, 16, 4);
  av_kernel<<<g3, 256, 0, stream>>>(x, wvb, attb, wpb, (float*)d_out);
}